// Round 6
// baseline (402.860 us; speedup 1.0000x reference)
//
#include <hip/hip_runtime.h>

#define NN 10000
#define BB 8
#define EE 160000
#define DH 128
#define LN_EPS 1e-5f

typedef unsigned short ushort_t;
typedef unsigned int uint_t;

typedef __bf16 bf16x8 __attribute__((ext_vector_type(8)));
typedef float floatx4 __attribute__((ext_vector_type(4)));

__device__ __forceinline__ float b2f(uint_t u) { return __uint_as_float(u << 16); }
__device__ __forceinline__ ushort_t f2b(float f) {
    uint_t u = __float_as_uint(f);
    return (ushort_t)((u + 0x7fffu + ((u >> 16) & 1u)) >> 16);
}
__device__ __forceinline__ uint_t pack2(float lo, float hi) {
    return (uint_t)f2b(lo) | ((uint_t)f2b(hi) << 16);
}
__device__ __forceinline__ float sigm(float x) { return 1.0f / (1.0f + __expf(-x)); }
__device__ __forceinline__ float tanh_fast(float x) {
    float ex = __expf(2.0f * x);
    return 1.0f - 2.0f / (ex + 1.0f);
}

// ---------------- CSR build ----------------

__global__ void count_deg(const int* __restrict__ ei, int* __restrict__ cnt) {
    int e = blockIdx.x * 256 + threadIdx.x;
    if (e < EE) atomicAdd(&cnt[ei[EE + e]], 1);
}

__global__ __launch_bounds__(256) void scan1(const int* __restrict__ cnt,
                                             int* __restrict__ offs,
                                             int* __restrict__ bsum) {
    __shared__ int s[256];
    const int t = threadIdx.x, idx = blockIdx.x * 256 + t;
    int x = (idx < NN) ? cnt[idx] : 0;
    s[t] = x;
    __syncthreads();
    for (int o = 1; o < 256; o <<= 1) {
        int v = s[t];
        int u = (t >= o) ? s[t - o] : 0;
        __syncthreads();
        s[t] = v + u;
        __syncthreads();
    }
    if (idx < NN) offs[idx] = s[t] - x;  // block-local exclusive
    if (t == 255) bsum[blockIdx.x] = s[255];
}

__global__ __launch_bounds__(64) void scan2(int* __restrict__ bsum, int* __restrict__ offs) {
    __shared__ int sb[40];
    const int t = threadIdx.x;
    if (t < 40) sb[t] = bsum[t];
    __syncthreads();
    if (t == 0) {
        int acc = 0;
        for (int i = 0; i < 40; ++i) {
            int v = sb[i];
            sb[i] = acc;
            acc += v;
        }
        offs[NN] = EE;
    }
    __syncthreads();
    if (t < 40) bsum[t] = sb[t];
}

__global__ __launch_bounds__(256) void scan3(const int* __restrict__ cnt,
                                             const int* __restrict__ bsum,
                                             int* __restrict__ offs,
                                             int* __restrict__ cursor,
                                             float* __restrict__ dis) {
    const int idx = blockIdx.x * 256 + threadIdx.x;
    if (idx < NN) {
        int off = offs[idx] + bsum[blockIdx.x];
        offs[idx] = off;
        cursor[idx] = off;
        dis[idx] = rsqrtf((float)(cnt[idx] + 1));
    }
}

// csr: src index + bf16(dis[src]) weight
__global__ void fill_csr(const int* __restrict__ ei, int* __restrict__ cursor,
                         const float* __restrict__ dis, int* __restrict__ csr_src,
                         ushort_t* __restrict__ csr_w) {
    int e = blockIdx.x * 256 + threadIdx.x;
    if (e < EE) {
        int s = ei[e];
        int d = ei[EE + e];
        int pos = atomicAdd(&cursor[d], 1);
        csr_src[pos] = s;
        csr_w[pos] = f2b(dis[s]);
    }
}

// ---------------- weight transpose+convert: Wt[col][k] bf16 ----------------

__global__ __launch_bounds__(256) void wt_k(const float* __restrict__ Wz,
                                            const float* __restrict__ Wr,
                                            const float* __restrict__ Wc,
                                            ushort_t* __restrict__ Wt_zr,
                                            ushort_t* __restrict__ Wt_c) {
    const int col = blockIdx.x, k = threadIdx.x;
    if (col < 256) {
        float v = (col < 128) ? Wz[(size_t)k * 128 + col] : Wr[(size_t)k * 128 + col - 128];
        Wt_zr[(size_t)col * 256 + k] = f2b(v);
    } else {
        int c2 = col - 256;
        Wt_c[(size_t)c2 * 256 + k] = f2b(Wc[(size_t)k * 128 + c2]);
    }
}

// ---------------- pack x,h -> bf16 (streaming) ----------------

__global__ __launch_bounds__(256) void pack_k(const float* __restrict__ x,
                                              const float* __restrict__ h,
                                              ushort_t* __restrict__ xb,
                                              ushort_t* __restrict__ hb) {
    const size_t o = ((size_t)blockIdx.x * 256 + threadIdx.x) * 4;
    float4 vx = *(const float4*)(x + o);
    uint2 px;
    px.x = pack2(vx.x, vx.y);
    px.y = pack2(vx.z, vx.w);
    *(uint2*)(xb + o) = px;
    float4 vh = *(const float4*)(h + o);
    uint2 ph;
    ph.x = pack2(vh.x, vh.y);
    ph.y = pack2(vh.z, vh.w);
    *(uint2*)(hb + o) = ph;
}

// ---------------- generic 128-wide bf16 gather, chunk-64 scalarized ----------------
// dst[b,n] = dis[n] * ( sum_e dis[s]*src[b,s] + dis[n]*src[b,n] )
// One wave per (b,n); batch = blockIdx&7 pins 2.56 MB slice per XCD (L2-resident).
// Edge metadata loaded coalesced 64-at-a-time, broadcast via v_readlane -> row
// address is wave-uniform (SGPR base + constant lane offset).

__global__ __launch_bounds__(256) void gather_b(
    const ushort_t* __restrict__ src, const int* __restrict__ offs,
    const int* __restrict__ csr_src, const ushort_t* __restrict__ csr_w,
    const float* __restrict__ dis, ushort_t* __restrict__ dst) {
    const int tid = threadIdx.x, lane = tid & 63;
    const int b = blockIdx.x & 7;
    const int n = (blockIdx.x >> 3) * 4 + (tid >> 6);
    const ushort_t* srcb = src + (size_t)b * NN * 128;  // wave-uniform base
    const int lo = lane * 2;

    const float dn = dis[n];
    float a0, a1;
    {
        uint_t u = *(const uint_t*)(srcb + (size_t)n * 128 + lo);
        a0 = dn * __uint_as_float(u << 16);
        a1 = dn * __uint_as_float(u & 0xffff0000u);
    }

    const int e0 = offs[n], e1 = offs[n + 1];
    for (int ch = e0; ch < e1; ch += 64) {
        const int rem = e1 - ch;
        int idx = 0;
        int wbits = 0;
        if (lane < rem) {
            idx = csr_src[ch + lane];
            wbits = (int)((uint_t)csr_w[ch + lane] << 16);
        }
        const int m = rem < 64 ? rem : 64;
#pragma unroll 4
        for (int i = 0; i < m; ++i) {
            const int s = __builtin_amdgcn_readlane(idx, i);
            const float w = __uint_as_float((uint_t)__builtin_amdgcn_readlane(wbits, i));
            const ushort_t* row = srcb + (size_t)s * 128;  // uniform pointer
            uint_t u = *(const uint_t*)(row + lo);
            a0 += w * __uint_as_float(u << 16);
            a1 += w * __uint_as_float(u & 0xffff0000u);
        }
    }
    a0 *= dn;
    a1 *= dn;
    *(uint_t*)(dst + ((size_t)b * NN + n) * 128 + lo) = pack2(a0, a1);
}

// ---------------- GEMM 128x128 tile, K=256 = [A1 | A2] @ Wt, fused epilogues ------
// PHASE 0: mode=blockIdx.y (0: z=sigma->z_buf bf16; 1: r=sigma, rh=r*h->rh bf16)
// PHASE 1: mode 2: tanh, GRU blend, LayerNorm -> out f32

template <int PHASE>
__global__ __launch_bounds__(256) void gemm_k(
    const ushort_t* __restrict__ A1, const ushort_t* __restrict__ A2,
    const ushort_t* __restrict__ Wt, const float* __restrict__ bz,
    const float* __restrict__ br, const float* __restrict__ bc,
    const float* __restrict__ h_prev, const ushort_t* __restrict__ z_in,
    const float* __restrict__ gamma, const float* __restrict__ beta,
    ushort_t* __restrict__ z_out, ushort_t* __restrict__ rh_out,
    float* __restrict__ f_out) {
    __shared__ __align__(16) ushort_t As[128 * 72];
    __shared__ __align__(16) ushort_t Bs[128 * 72];
    const int tid = threadIdx.x;
    const int rb0 = blockIdx.x * 128;
    const int mode = (PHASE == 1) ? 2 : blockIdx.y;
    const int cb0 = (mode == 1) ? 128 : 0;

    const int wv = tid >> 6, lane = tid & 63;
    const int l15 = lane & 15, q = lane >> 4;
    const int sr = tid >> 1;
    const int kh = (tid & 1) * 32;

    floatx4 acc[2][8];
#pragma unroll
    for (int i = 0; i < 2; ++i)
#pragma unroll
        for (int j = 0; j < 8; ++j) acc[i][j] = (floatx4){0.f, 0.f, 0.f, 0.f};

    for (int k0 = 0; k0 < 256; k0 += 64) {
        {
            const int kg = k0 + kh;
            const ushort_t* s = (kg < 128) ? (A1 + (size_t)(rb0 + sr) * 128 + kg)
                                           : (A2 + (size_t)(rb0 + sr) * 128 + (kg - 128));
            ushort_t* dst = &As[sr * 72 + kh];
#pragma unroll
            for (int i = 0; i < 4; ++i) *(uint4*)(dst + i * 8) = *(const uint4*)(s + i * 8);
        }
        {
            const ushort_t* s = Wt + (size_t)(cb0 + sr) * 256 + k0 + kh;
            ushort_t* dst = &Bs[sr * 72 + kh];
#pragma unroll
            for (int i = 0; i < 4; ++i) *(uint4*)(dst + i * 8) = *(const uint4*)(s + i * 8);
        }
        __syncthreads();
#pragma unroll
        for (int ks = 0; ks < 2; ++ks) {
            const int ko = ks * 32 + q * 8;
            bf16x8 a0 = *(const bf16x8*)&As[(wv * 32 + l15) * 72 + ko];
            bf16x8 a1 = *(const bf16x8*)&As[(wv * 32 + 16 + l15) * 72 + ko];
#pragma unroll
            for (int j = 0; j < 8; ++j) {
                bf16x8 b = *(const bf16x8*)&Bs[(j * 16 + l15) * 72 + ko];
                acc[0][j] = __builtin_amdgcn_mfma_f32_16x16x32_bf16(a0, b, acc[0][j], 0, 0, 0);
                acc[1][j] = __builtin_amdgcn_mfma_f32_16x16x32_bf16(a1, b, acc[1][j], 0, 0, 0);
            }
        }
        __syncthreads();
    }

    // C/D: col = j*16 + l15, row = rb0 + wv*32 + i*16 + q*4 + v
    if (mode == 0) {
        float bv[8];
#pragma unroll
        for (int j = 0; j < 8; ++j) bv[j] = bz[j * 16 + l15];
#pragma unroll
        for (int i = 0; i < 2; ++i)
#pragma unroll
            for (int j = 0; j < 8; ++j)
#pragma unroll
                for (int v = 0; v < 4; ++v) {
                    int row = rb0 + wv * 32 + i * 16 + q * 4 + v;
                    z_out[(size_t)row * 128 + j * 16 + l15] = f2b(sigm(acc[i][j][v] + bv[j]));
                }
    } else if (mode == 1) {
        float bv[8];
#pragma unroll
        for (int j = 0; j < 8; ++j) bv[j] = br[j * 16 + l15];
#pragma unroll
        for (int i = 0; i < 2; ++i)
#pragma unroll
            for (int j = 0; j < 8; ++j)
#pragma unroll
                for (int v = 0; v < 4; ++v) {
                    int row = rb0 + wv * 32 + i * 16 + q * 4 + v;
                    float r = sigm(acc[i][j][v] + bv[j]);
                    float hh = h_prev[(size_t)row * 128 + j * 16 + l15];
                    rh_out[(size_t)row * 128 + j * 16 + l15] = f2b(r * hh);
                }
    } else {
        float bv[8], gv[8], bev[8];
#pragma unroll
        for (int j = 0; j < 8; ++j) {
            bv[j] = bc[j * 16 + l15];
            gv[j] = gamma[j * 16 + l15];
            bev[j] = beta[j * 16 + l15];
        }
#pragma unroll
        for (int i = 0; i < 2; ++i)
#pragma unroll
            for (int v = 0; v < 4; ++v) {
                const int row = rb0 + wv * 32 + i * 16 + q * 4 + v;
                float hn[8];
                float s = 0.f;
#pragma unroll
                for (int j = 0; j < 8; ++j) {
                    float hc = tanh_fast(acc[i][j][v] + bv[j]);
                    float zz = b2f((uint_t)z_in[(size_t)row * 128 + j * 16 + l15]);
                    float hh = h_prev[(size_t)row * 128 + j * 16 + l15];
                    hn[j] = (1.0f - zz) * hh + zz * hc;
                    s += hn[j];
                }
#pragma unroll
                for (int o = 8; o > 0; o >>= 1) s += __shfl_xor(s, o);  // 16-lane quad
                float mu = s * (1.0f / 128.0f);
                float vv = 0.f;
#pragma unroll
                for (int j = 0; j < 8; ++j) {
                    float d = hn[j] - mu;
                    vv += d * d;
                }
#pragma unroll
                for (int o = 8; o > 0; o >>= 1) vv += __shfl_xor(vv, o);
                float inv = rsqrtf(vv * (1.0f / 128.0f) + LN_EPS);
#pragma unroll
                for (int j = 0; j < 8; ++j)
                    f_out[(size_t)row * 128 + j * 16 + l15] =
                        (hn[j] - mu) * inv * gv[j] + bev[j];
            }
    }
}

// ---------------- launch ----------------

extern "C" void kernel_launch(void* const* d_in, const int* in_sizes, int n_in,
                              void* d_out, int out_size, void* d_ws, size_t ws_size,
                              hipStream_t stream) {
    const float* x = (const float*)d_in[0];
    const int* ei = (const int*)d_in[1];
    const float* h = (const float*)d_in[2];
    const float* Wz = (const float*)d_in[3];
    const float* bz = (const float*)d_in[4];
    const float* Wr = (const float*)d_in[5];
    const float* br = (const float*)d_in[6];
    const float* Wc = (const float*)d_in[7];
    const float* bcv = (const float*)d_in[8];
    const float* gamma = (const float*)d_in[9];
    const float* beta = (const float*)d_in[10];
    float* out = (float*)d_out;

    char* w = (char*)d_ws;
    int* offs = (int*)(w + 0);                    //    40,004 B
    float* dis = (float*)(w + 40960);             //    40,000 B
    int* csr_src = (int*)(w + 81920);             //   640,000 B
    ushort_t* csr_w = (ushort_t*)(w + 721920);    //   320,000 B
    ushort_t* Wt_zr = (ushort_t*)(w + 1041920);   //   131,072 B
    ushort_t* Wt_c = (ushort_t*)(w + 1172992);    //    65,536 B
    ushort_t* xb = (ushort_t*)(w + 1239040);      // 20,480,000 B
    ushort_t* hb = (ushort_t*)(w + 21719040);     // 20,480,000 B
    ushort_t* agg_x = (ushort_t*)(w + 42199040);  // 20,480,000 B
    ushort_t* agg_h = (ushort_t*)(w + 62679040);  // 20,480,000 B -> end 83,159,040
    // aliases (strict lifetime reuse on one stream):
    int* cnt = (int*)(w + 1239040);     // dead after fill_csr, before pack_k
    int* cursor = (int*)(w + 1280000);  // dead after fill_csr
    int* bsum = (int*)(w + 1320000);    // dead after scan3
    ushort_t* z_buf = xb;   // xb dead after gather_b(xb); written by gemm<0>
    ushort_t* rh_bf = hb;   // hb dead after gather_b(hb); written by gemm<0>
    ushort_t* agg_rh = agg_h;  // agg_h dead after gemm<0>

    hipMemsetAsync(cnt, 0, NN * sizeof(int), stream);
    count_deg<<<EE / 256, 256, 0, stream>>>(ei, cnt);
    scan1<<<40, 256, 0, stream>>>(cnt, offs, bsum);
    scan2<<<1, 64, 0, stream>>>(bsum, offs);
    scan3<<<40, 256, 0, stream>>>(cnt, bsum, offs, cursor, dis);
    fill_csr<<<EE / 256, 256, 0, stream>>>(ei, cursor, dis, csr_src, csr_w);
    wt_k<<<384, 256, 0, stream>>>(Wz, Wr, Wc, Wt_zr, Wt_c);
    pack_k<<<10000, 256, 0, stream>>>(x, h, xb, hb);

    gather_b<<<(BB * NN) / 4, 256, 0, stream>>>(xb, offs, csr_src, csr_w, dis, agg_x);
    gather_b<<<(BB * NN) / 4, 256, 0, stream>>>(hb, offs, csr_src, csr_w, dis, agg_h);
    // z (y=0) and rh (y=1) from one GEMM over [agg_x|agg_h]
    gemm_k<0><<<dim3(80000 / 128, 2), 256, 0, stream>>>(
        agg_x, agg_h, Wt_zr, bz, br, bcv, h, (const ushort_t*)0, gamma, beta,
        z_buf, rh_bf, (float*)0);
    gather_b<<<(BB * NN) / 4, 256, 0, stream>>>(rh_bf, offs, csr_src, csr_w, dis, agg_rh);
    // out = LN(GRU(tanh([agg_x|agg_rh]@Wc + bc)))
    gemm_k<1><<<dim3(80000 / 128, 1), 256, 0, stream>>>(
        agg_x, agg_rh, Wt_c, bz, br, bcv, h, z_buf, gamma, beta,
        (ushort_t*)0, (ushort_t*)0, out);
}

// Round 7
// 332.183 us; speedup vs baseline: 1.2128x; 1.2128x over previous
//
#include <hip/hip_runtime.h>

#define NN 10000
#define BB 8
#define EE 160000
#define DH 128
#define LN_EPS 1e-5f

typedef unsigned short ushort_t;
typedef unsigned int uint_t;

typedef __bf16 bf16x8 __attribute__((ext_vector_type(8)));
typedef float floatx4 __attribute__((ext_vector_type(4)));

__device__ __forceinline__ float b2f(uint_t u) { return __uint_as_float(u << 16); }
__device__ __forceinline__ ushort_t f2b(float f) {
    uint_t u = __float_as_uint(f);
    return (ushort_t)((u + 0x7fffu + ((u >> 16) & 1u)) >> 16);
}
__device__ __forceinline__ uint_t pack2(float lo, float hi) {
    return (uint_t)f2b(lo) | ((uint_t)f2b(hi) << 16);
}
__device__ __forceinline__ float sigm(float x) { return 1.0f / (1.0f + __expf(-x)); }
__device__ __forceinline__ float tanh_fast(float x) {
    float ex = __expf(2.0f * x);
    return 1.0f - 2.0f / (ex + 1.0f);
}
// accumulate 8 bf16 (uint4) with weight w
__device__ __forceinline__ void acc8(float* a, float w, uint4 v) {
    a[0] += w * __uint_as_float(v.x << 16);
    a[1] += w * __uint_as_float(v.x & 0xffff0000u);
    a[2] += w * __uint_as_float(v.y << 16);
    a[3] += w * __uint_as_float(v.y & 0xffff0000u);
    a[4] += w * __uint_as_float(v.z << 16);
    a[5] += w * __uint_as_float(v.z & 0xffff0000u);
    a[6] += w * __uint_as_float(v.w << 16);
    a[7] += w * __uint_as_float(v.w & 0xffff0000u);
}

// ---------------- CSR build ----------------

__global__ void count_deg(const int* __restrict__ ei, int* __restrict__ cnt) {
    int e = blockIdx.x * 256 + threadIdx.x;
    if (e < EE) atomicAdd(&cnt[ei[EE + e]], 1);
}

__global__ __launch_bounds__(256) void scan1(const int* __restrict__ cnt,
                                             int* __restrict__ offs,
                                             int* __restrict__ bsum) {
    __shared__ int s[256];
    const int t = threadIdx.x, idx = blockIdx.x * 256 + t;
    int x = (idx < NN) ? cnt[idx] : 0;
    s[t] = x;
    __syncthreads();
    for (int o = 1; o < 256; o <<= 1) {
        int v = s[t];
        int u = (t >= o) ? s[t - o] : 0;
        __syncthreads();
        s[t] = v + u;
        __syncthreads();
    }
    if (idx < NN) offs[idx] = s[t] - x;  // block-local exclusive
    if (t == 255) bsum[blockIdx.x] = s[255];
}

__global__ __launch_bounds__(64) void scan2(int* __restrict__ bsum, int* __restrict__ offs) {
    __shared__ int sb[40];
    const int t = threadIdx.x;
    if (t < 40) sb[t] = bsum[t];
    __syncthreads();
    if (t == 0) {
        int acc = 0;
        for (int i = 0; i < 40; ++i) {
            int v = sb[i];
            sb[i] = acc;
            acc += v;
        }
        offs[NN] = EE;
    }
    __syncthreads();
    if (t < 40) bsum[t] = sb[t];
}

__global__ __launch_bounds__(256) void scan3(const int* __restrict__ cnt,
                                             const int* __restrict__ bsum,
                                             int* __restrict__ offs,
                                             int* __restrict__ cursor,
                                             float* __restrict__ dis) {
    const int idx = blockIdx.x * 256 + threadIdx.x;
    if (idx < NN) {
        int off = offs[idx] + bsum[blockIdx.x];
        offs[idx] = off;
        cursor[idx] = off;
        dis[idx] = rsqrtf((float)(cnt[idx] + 1));
    }
}

// csr: src index + bf16(dis[src]) weight
__global__ void fill_csr(const int* __restrict__ ei, int* __restrict__ cursor,
                         const float* __restrict__ dis, int* __restrict__ csr_src,
                         ushort_t* __restrict__ csr_w) {
    int e = blockIdx.x * 256 + threadIdx.x;
    if (e < EE) {
        int s = ei[e];
        int d = ei[EE + e];
        int pos = atomicAdd(&cursor[d], 1);
        csr_src[pos] = s;
        csr_w[pos] = f2b(dis[s]);
    }
}

// ---------------- pack x,h -> bf16 + weight transpose (merged) ----------------
// blocks < 10000: pack 1024 elements of x and h each.
// blocks 10000..10383: transpose-convert one weight column.

__global__ __launch_bounds__(256) void packwt_k(const float* __restrict__ x,
                                                const float* __restrict__ h,
                                                ushort_t* __restrict__ xb,
                                                ushort_t* __restrict__ hb,
                                                const float* __restrict__ Wz,
                                                const float* __restrict__ Wr,
                                                const float* __restrict__ Wc,
                                                ushort_t* __restrict__ Wt_zr,
                                                ushort_t* __restrict__ Wt_c) {
    if (blockIdx.x < 10000) {
        const size_t o = ((size_t)blockIdx.x * 256 + threadIdx.x) * 4;
        float4 vx = *(const float4*)(x + o);
        uint2 px;
        px.x = pack2(vx.x, vx.y);
        px.y = pack2(vx.z, vx.w);
        *(uint2*)(xb + o) = px;
        float4 vh = *(const float4*)(h + o);
        uint2 ph;
        ph.x = pack2(vh.x, vh.y);
        ph.y = pack2(vh.z, vh.w);
        *(uint2*)(hb + o) = ph;
    } else {
        const int col = blockIdx.x - 10000, k = threadIdx.x;
        if (col < 256) {
            float v = (col < 128) ? Wz[(size_t)k * 128 + col]
                                  : Wr[(size_t)k * 128 + col - 128];
            Wt_zr[(size_t)col * 256 + k] = f2b(v);
        } else {
            int c2 = col - 256;
            Wt_c[(size_t)c2 * 256 + k] = f2b(Wc[(size_t)k * 128 + c2]);
        }
    }
}

// ---------------- gather4: 4 edges/iter x 16 lanes x 8 bf16 cols ----------------
// dst[b,n] = dis[n] * ( sum_e dis[s]*src[b,s] + dis[n]*src[b,n] )
// One wave per (b,n). Group g = lane>>4 owns edge i*4+g; one global_load_dwordx4
// per buffer fetches 4 different rows (1 KB). Metadata chunk-preloaded coalesced,
// broadcast per-group via ds_bpermute. NB=2 gathers two buffers in one pass.

template <int NB>
__global__ __launch_bounds__(256) void gather4(
    const ushort_t* __restrict__ src0, const ushort_t* __restrict__ src1,
    const int* __restrict__ offs, const int* __restrict__ csr_src,
    const ushort_t* __restrict__ csr_w, const float* __restrict__ dis,
    ushort_t* __restrict__ dst0, ushort_t* __restrict__ dst1) {
    const int tid = threadIdx.x, lane = tid & 63;
    const int b = blockIdx.x & 7;
    const int n = (blockIdx.x >> 3) * 4 + (tid >> 6);
    const int g = lane >> 4, il = lane & 15;
    const ushort_t* base0 = src0 + (size_t)b * NN * 128;
    const ushort_t* base1 = (NB == 2) ? (src1 + (size_t)b * NN * 128) : base0;

    float a0[8], a1[8];
#pragma unroll
    for (int j = 0; j < 8; ++j) {
        a0[j] = 0.f;
        a1[j] = 0.f;
    }

    const float dn = dis[n];
    if (g == 0) {  // self row, weight dn inside the sum
        const uint_t off = (uint_t)n * 128u + (uint_t)il * 8u;
        uint4 v = *(const uint4*)(base0 + off);
        acc8(a0, dn, v);
        if (NB == 2) {
            uint4 vv = *(const uint4*)(base1 + off);
            acc8(a1, dn, vv);
        }
    }

    const int e0 = offs[n], e1 = offs[n + 1];
    for (int ch = e0; ch < e1; ch += 64) {
        const int rem = e1 - ch;
        int idx = 0, wb = 0;
        if (lane < rem) {
            idx = csr_src[ch + lane];
            wb = (int)((uint_t)csr_w[ch + lane] << 16);
        }
        const int m = rem < 64 ? rem : 64;
        const int groups = (m + 3) >> 2;
        int pidx = g * 4;  // bpermute byte index for edge i*4+g
#pragma unroll 2
        for (int i = 0; i < groups; ++i) {
            const int s = __builtin_amdgcn_ds_bpermute(pidx, idx);
            const float w =
                __uint_as_float((uint_t)__builtin_amdgcn_ds_bpermute(pidx, wb));
            pidx += 16;
            const uint_t off = (uint_t)s * 128u + (uint_t)il * 8u;
            uint4 v = *(const uint4*)(base0 + off);
            acc8(a0, w, v);
            if (NB == 2) {
                uint4 vv = *(const uint4*)(base1 + off);
                acc8(a1, w, vv);
            }
        }
    }

#pragma unroll
    for (int j = 0; j < 8; ++j) {
        a0[j] *= dn;
        a0[j] += __shfl_xor(a0[j], 16);
        a0[j] += __shfl_xor(a0[j], 32);
    }
    if (NB == 2) {
#pragma unroll
        for (int j = 0; j < 8; ++j) {
            a1[j] *= dn;
            a1[j] += __shfl_xor(a1[j], 16);
            a1[j] += __shfl_xor(a1[j], 32);
        }
    }

    if (lane < 16) {
        const size_t o = ((size_t)b * NN + n) * 128 + (size_t)il * 8;
        uint4 st;
        st.x = pack2(a0[0], a0[1]);
        st.y = pack2(a0[2], a0[3]);
        st.z = pack2(a0[4], a0[5]);
        st.w = pack2(a0[6], a0[7]);
        *(uint4*)(dst0 + o) = st;
        if (NB == 2) {
            uint4 st1;
            st1.x = pack2(a1[0], a1[1]);
            st1.y = pack2(a1[2], a1[3]);
            st1.z = pack2(a1[4], a1[5]);
            st1.w = pack2(a1[6], a1[7]);
            *(uint4*)(dst1 + o) = st1;
        }
    }
}

// ---------------- GEMM 128x128 tile, K=256 = [A1 | A2] @ Wt, fused epilogues ------
// PHASE 0: mode=blockIdx.y (0: z=sigma->z_buf bf16; 1: r=sigma, rh=r*h->rh bf16)
// PHASE 1: mode 2: tanh, GRU blend, LayerNorm -> out f32

template <int PHASE>
__global__ __launch_bounds__(256) void gemm_k(
    const ushort_t* __restrict__ A1, const ushort_t* __restrict__ A2,
    const ushort_t* __restrict__ Wt, const float* __restrict__ bz,
    const float* __restrict__ br, const float* __restrict__ bc,
    const float* __restrict__ h_prev, const ushort_t* __restrict__ z_in,
    const float* __restrict__ gamma, const float* __restrict__ beta,
    ushort_t* __restrict__ z_out, ushort_t* __restrict__ rh_out,
    float* __restrict__ f_out) {
    __shared__ __align__(16) ushort_t As[128 * 72];
    __shared__ __align__(16) ushort_t Bs[128 * 72];
    const int tid = threadIdx.x;
    const int rb0 = blockIdx.x * 128;
    const int mode = (PHASE == 1) ? 2 : blockIdx.y;
    const int cb0 = (mode == 1) ? 128 : 0;

    const int wv = tid >> 6, lane = tid & 63;
    const int l15 = lane & 15, q = lane >> 4;
    const int sr = tid >> 1;
    const int kh = (tid & 1) * 32;

    floatx4 acc[2][8];
#pragma unroll
    for (int i = 0; i < 2; ++i)
#pragma unroll
        for (int j = 0; j < 8; ++j) acc[i][j] = (floatx4){0.f, 0.f, 0.f, 0.f};

    for (int k0 = 0; k0 < 256; k0 += 64) {
        {
            const int kg = k0 + kh;
            const ushort_t* s = (kg < 128) ? (A1 + (size_t)(rb0 + sr) * 128 + kg)
                                           : (A2 + (size_t)(rb0 + sr) * 128 + (kg - 128));
            ushort_t* dst = &As[sr * 72 + kh];
#pragma unroll
            for (int i = 0; i < 4; ++i) *(uint4*)(dst + i * 8) = *(const uint4*)(s + i * 8);
        }
        {
            const ushort_t* s = Wt + (size_t)(cb0 + sr) * 256 + k0 + kh;
            ushort_t* dst = &Bs[sr * 72 + kh];
#pragma unroll
            for (int i = 0; i < 4; ++i) *(uint4*)(dst + i * 8) = *(const uint4*)(s + i * 8);
        }
        __syncthreads();
#pragma unroll
        for (int ks = 0; ks < 2; ++ks) {
            const int ko = ks * 32 + q * 8;
            bf16x8 a0 = *(const bf16x8*)&As[(wv * 32 + l15) * 72 + ko];
            bf16x8 a1 = *(const bf16x8*)&As[(wv * 32 + 16 + l15) * 72 + ko];
#pragma unroll
            for (int j = 0; j < 8; ++j) {
                bf16x8 b = *(const bf16x8*)&Bs[(j * 16 + l15) * 72 + ko];
                acc[0][j] = __builtin_amdgcn_mfma_f32_16x16x32_bf16(a0, b, acc[0][j], 0, 0, 0);
                acc[1][j] = __builtin_amdgcn_mfma_f32_16x16x32_bf16(a1, b, acc[1][j], 0, 0, 0);
            }
        }
        __syncthreads();
    }

    // C/D: col = j*16 + l15, row = rb0 + wv*32 + i*16 + q*4 + v
    if (mode == 0) {
        float bv[8];
#pragma unroll
        for (int j = 0; j < 8; ++j) bv[j] = bz[j * 16 + l15];
#pragma unroll
        for (int i = 0; i < 2; ++i)
#pragma unroll
            for (int j = 0; j < 8; ++j)
#pragma unroll
                for (int v = 0; v < 4; ++v) {
                    int row = rb0 + wv * 32 + i * 16 + q * 4 + v;
                    z_out[(size_t)row * 128 + j * 16 + l15] = f2b(sigm(acc[i][j][v] + bv[j]));
                }
    } else if (mode == 1) {
        float bv[8];
#pragma unroll
        for (int j = 0; j < 8; ++j) bv[j] = br[j * 16 + l15];
#pragma unroll
        for (int i = 0; i < 2; ++i)
#pragma unroll
            for (int j = 0; j < 8; ++j)
#pragma unroll
                for (int v = 0; v < 4; ++v) {
                    int row = rb0 + wv * 32 + i * 16 + q * 4 + v;
                    float r = sigm(acc[i][j][v] + bv[j]);
                    float hh = h_prev[(size_t)row * 128 + j * 16 + l15];
                    rh_out[(size_t)row * 128 + j * 16 + l15] = f2b(r * hh);
                }
    } else {
        float bv[8], gv[8], bev[8];
#pragma unroll
        for (int j = 0; j < 8; ++j) {
            bv[j] = bc[j * 16 + l15];
            gv[j] = gamma[j * 16 + l15];
            bev[j] = beta[j * 16 + l15];
        }
#pragma unroll
        for (int i = 0; i < 2; ++i)
#pragma unroll
            for (int v = 0; v < 4; ++v) {
                const int row = rb0 + wv * 32 + i * 16 + q * 4 + v;
                float hn[8];
                float s = 0.f;
#pragma unroll
                for (int j = 0; j < 8; ++j) {
                    float hc = tanh_fast(acc[i][j][v] + bv[j]);
                    float zz = b2f((uint_t)z_in[(size_t)row * 128 + j * 16 + l15]);
                    float hh = h_prev[(size_t)row * 128 + j * 16 + l15];
                    hn[j] = (1.0f - zz) * hh + zz * hc;
                    s += hn[j];
                }
#pragma unroll
                for (int o = 8; o > 0; o >>= 1) s += __shfl_xor(s, o);  // 16-lane quad
                float mu = s * (1.0f / 128.0f);
                float vv = 0.f;
#pragma unroll
                for (int j = 0; j < 8; ++j) {
                    float d = hn[j] - mu;
                    vv += d * d;
                }
#pragma unroll
                for (int o = 8; o > 0; o >>= 1) vv += __shfl_xor(vv, o);
                float inv = rsqrtf(vv * (1.0f / 128.0f) + LN_EPS);
#pragma unroll
                for (int j = 0; j < 8; ++j)
                    f_out[(size_t)row * 128 + j * 16 + l15] =
                        (hn[j] - mu) * inv * gv[j] + bev[j];
            }
    }
}

// ---------------- launch ----------------

extern "C" void kernel_launch(void* const* d_in, const int* in_sizes, int n_in,
                              void* d_out, int out_size, void* d_ws, size_t ws_size,
                              hipStream_t stream) {
    const float* x = (const float*)d_in[0];
    const int* ei = (const int*)d_in[1];
    const float* h = (const float*)d_in[2];
    const float* Wz = (const float*)d_in[3];
    const float* bz = (const float*)d_in[4];
    const float* Wr = (const float*)d_in[5];
    const float* br = (const float*)d_in[6];
    const float* Wc = (const float*)d_in[7];
    const float* bcv = (const float*)d_in[8];
    const float* gamma = (const float*)d_in[9];
    const float* beta = (const float*)d_in[10];
    float* out = (float*)d_out;

    char* w = (char*)d_ws;
    int* offs = (int*)(w + 0);                    //    40,004 B
    float* dis = (float*)(w + 40960);             //    40,000 B
    int* csr_src = (int*)(w + 81920);             //   640,000 B
    ushort_t* csr_w = (ushort_t*)(w + 721920);    //   320,000 B
    ushort_t* Wt_zr = (ushort_t*)(w + 1041920);   //   131,072 B
    ushort_t* Wt_c = (ushort_t*)(w + 1172992);    //    65,536 B
    ushort_t* xb = (ushort_t*)(w + 1239040);      // 20,480,000 B
    ushort_t* hb = (ushort_t*)(w + 21719040);     // 20,480,000 B
    ushort_t* agg_x = (ushort_t*)(w + 42199040);  // 20,480,000 B
    ushort_t* agg_h = (ushort_t*)(w + 62679040);  // 20,480,000 B -> end 83,159,040
    // aliases (strict lifetime reuse on one stream):
    int* cnt = (int*)(w + 1239040);     // dead after fill_csr, before packwt_k
    int* cursor = (int*)(w + 1280000);  // dead after fill_csr
    int* bsum = (int*)(w + 1320000);    // dead after scan3
    ushort_t* z_buf = xb;      // xb dead after gather4<2>; written by gemm<0>
    ushort_t* rh_bf = hb;      // hb dead after gather4<2>; written by gemm<0>
    ushort_t* agg_rh = agg_h;  // agg_h dead after gemm<0>

    hipMemsetAsync(cnt, 0, NN * sizeof(int), stream);
    count_deg<<<EE / 256, 256, 0, stream>>>(ei, cnt);
    scan1<<<40, 256, 0, stream>>>(cnt, offs, bsum);
    scan2<<<1, 64, 0, stream>>>(bsum, offs);
    scan3<<<40, 256, 0, stream>>>(cnt, bsum, offs, cursor, dis);
    fill_csr<<<EE / 256, 256, 0, stream>>>(ei, cursor, dis, csr_src, csr_w);
    packwt_k<<<10384, 256, 0, stream>>>(x, h, xb, hb, Wz, Wr, Wc, Wt_zr, Wt_c);

    // agg_x, agg_h in one fused pass
    gather4<2><<<(BB * NN) / 4, 256, 0, stream>>>(xb, hb, offs, csr_src, csr_w, dis,
                                                  agg_x, agg_h);
    // z (y=0) and rh (y=1) from one GEMM over [agg_x|agg_h]
    gemm_k<0><<<dim3(80000 / 128, 2), 256, 0, stream>>>(
        agg_x, agg_h, Wt_zr, bz, br, bcv, h, (const ushort_t*)0, gamma, beta,
        z_buf, rh_bf, (float*)0);
    gather4<1><<<(BB * NN) / 4, 256, 0, stream>>>(rh_bf, (const ushort_t*)0, offs,
                                                  csr_src, csr_w, dis, agg_rh,
                                                  (ushort_t*)0);
    // out = LN(GRU(tanh([agg_x|agg_rh]@Wc + bc)))
    gemm_k<1><<<dim3(80000 / 128, 1), 256, 0, stream>>>(
        agg_x, agg_rh, Wt_c, bz, br, bcv, h, z_buf, gamma, beta,
        (ushort_t*)0, (ushort_t*)0, out);
}